// Round 2
// 255.892 us; speedup vs baseline: 1.0418x; 1.0418x over previous
//
#include <hip/hip_runtime.h>

#define BB 16
#define TT 4096
#define DD 512
#define CH 64               // rows per chunk in fused kernel
#define NY (TT/CH)          // 64 chunks per batch row
#define NEG (-1.0e30f)

// workspace float offsets
#define OFF_Q     64                         // 3*BB*DD
#define OFF_P0    (OFF_Q + 3*BB*DD)          // BB*TT      (level-0 dots for att)
#define OFF_M     (OFF_P0 + BB*TT)           // 3*BB*NY    (per-chunk local max)
#define OFF_S     (OFF_M + 3*BB*NY)          // 3*BB*NY    (per-chunk exp-sum)
#define OFF_MT    (OFF_S + 3*BB*NY)          // 64         (per-(i,b) global max)
#define OFF_TOT   (OFF_MT + 64)              // 64         (per-(i,b) total)
#define OFF_PART  (OFF_TOT + 64)             // 3*NY*BB*DD (pooled partials, 6.3MB)
#define OFF_POOL  (OFF_PART + 3*NY*BB*DD)    // 3*BB*DD

// ---------------- K1: mask layout detection + per-batch lengths --------------
// one block per batch; every block redundantly probes layout (cheap, parallel)
__global__ void __launch_bounds__(256) k_lengths(const unsigned char* __restrict__ mask,
                                                 int* __restrict__ lengths) {
    __shared__ int sflag;
    __shared__ int wsum[4];
    const int tid = threadIdx.x;
    const int b = blockIdx.x;
    if (tid == 0) sflag = 0;
    __syncthreads();
    // layout probe: any nonzero byte at offset %4 != 0 => byte (bool) layout.
    // int32 layout stores 0/1 so bytes 1..3 of every word are zero.
    const uint4* m4 = (const uint4*)mask;
    int f = 0;
    #pragma unroll 4
    for (int idx = tid; idx < BB * TT / 16; idx += 256) {
        const uint4 w = m4[idx];
        f |= (((w.x | w.y | w.z | w.w) & 0xFFFFFF00u) != 0u);
    }
    if (f) atomicOr(&sflag, 1);
    __syncthreads();
    const bool byte_layout = (sflag != 0);
    const int* m32 = (const int*)mask;
    int cnt = 0;
    if (byte_layout) {
        for (int t = tid; t < TT; t += 256) cnt += (mask[b * TT + t] != 0);
    } else {
        for (int t = tid; t < TT; t += 256) cnt += (m32[b * TT + t] != 0);
    }
    #pragma unroll
    for (int m = 32; m >= 1; m >>= 1) cnt += __shfl_xor(cnt, m, 64);
    if ((tid & 63) == 0) wsum[tid >> 6] = cnt;
    __syncthreads();
    if (tid == 0) lengths[b] = TT - (wsum[0] + wsum[1] + wsum[2] + wsum[3]);
}

// ------- K2: q[(i,b),d] = sum_e s_prev[b,e]*Vw[i,e,d]  (one block per (i,b)) -
// 1024 threads, 4-way e-split reduced in LDS (replaces k_q + k_q_reduce)
__global__ void __launch_bounds__(1024) k_q(const float* __restrict__ s_prev,
                                            const float* __restrict__ Vw,
                                            float* __restrict__ q) {
    __shared__ float red[4][DD];
    const int ib = blockIdx.x;            // i*BB+b, 48 blocks
    const int b = ib % BB;
    const int i = ib / BB;
    const int ec = threadIdx.x >> 8;      // e-quarter, wave-uniform
    const int d0 = threadIdx.x & 255;
    const float* sp = s_prev + b * DD + ec * 128;
    const float* W = Vw + (size_t)i * DD * DD + (size_t)(ec * 128) * DD;
    float a0 = 0.f, a1 = 0.f;
    #pragma unroll 4
    for (int e = 0; e < 128; e++) {
        const float se = sp[e];           // wave-uniform -> scalar load
        a0 += se * W[e * DD + d0];
        a1 += se * W[e * DD + d0 + 256];
    }
    red[ec][d0] = a0;
    red[ec][d0 + 256] = a1;
    __syncthreads();
    if (threadIdx.x < DD)
        q[(size_t)ib * DD + threadIdx.x] = red[0][threadIdx.x] + red[1][threadIdx.x]
                                         + red[2][threadIdx.x] + red[3][threadIdx.x];
}

// ---- K3 fused: dots + local windowed softmax + weighted pooling, 1 enc pass -
// Block = (b, chunk y): rows [t0, t0+CH) plus 2 boundary rows. 512 threads.
__global__ void __launch_bounds__(512, 4) k_fused(const float* __restrict__ enc,
                                                  const float* __restrict__ q,
                                                  const int* __restrict__ lengths,
                                                  float* __restrict__ p0,
                                                  float* __restrict__ mbuf,
                                                  float* __restrict__ sbuf,
                                                  float* __restrict__ part) {
    __shared__ float sp[CH + 2][3];   // per-row dots, 3 levels
    __shared__ float su[3][CH];       // raw exp weights
    const int b = blockIdx.x;
    const int y = blockIdx.y;
    const int t0 = y * CH;
    const int len = lengths[b];
    const int tid = threadIdx.x;
    if (t0 >= len) {                  // fully masked chunk (block-uniform)
        if (tid < 3) {
            mbuf[(size_t)(tid * BB + b) * NY + y] = NEG;
            sbuf[(size_t)(tid * BB + b) * NY + y] = 0.f;
        }
        return;
    }
    const int wv = tid >> 6, lane = tid & 63;

    // --- phase A: dots p_i[t] = enc[t] . q_i[b] for rows t0..t0+65 -----------
    const float4* q40 = (const float4*)(q + (size_t)(0 * BB + b) * DD);
    const float4* q41 = (const float4*)(q + (size_t)(1 * BB + b) * DD);
    const float4* q42 = (const float4*)(q + (size_t)(2 * BB + b) * DD);
    const float4 qa0 = q40[lane], qb0 = q40[64 + lane];
    const float4 qa1 = q41[lane], qb1 = q41[64 + lane];
    const float4 qa2 = q42[lane], qb2 = q42[64 + lane];

    auto row_task = [&](const int r, const bool wp0) {
        const int t = t0 + r;
        float d0 = 0.f, d1 = 0.f, d2 = 0.f;
        if (t < len) {                                  // wave-uniform
            const float4* e4 = (const float4*)(enc + ((size_t)b * TT + t) * DD);
            const float4 x0 = e4[lane], x1 = e4[64 + lane];
            d0 = x0.x*qa0.x + x0.y*qa0.y + x0.z*qa0.z + x0.w*qa0.w
               + x1.x*qb0.x + x1.y*qb0.y + x1.z*qb0.z + x1.w*qb0.w;
            d1 = x0.x*qa1.x + x0.y*qa1.y + x0.z*qa1.z + x0.w*qa1.w
               + x1.x*qb1.x + x1.y*qb1.y + x1.z*qb1.z + x1.w*qb1.w;
            d2 = x0.x*qa2.x + x0.y*qa2.y + x0.z*qa2.z + x0.w*qa2.w
               + x1.x*qb2.x + x1.y*qb2.y + x1.z*qb2.z + x1.w*qb2.w;
            #pragma unroll
            for (int m = 32; m >= 1; m >>= 1) {
                d0 += __shfl_xor(d0, m, 64);
                d1 += __shfl_xor(d1, m, 64);
                d2 += __shfl_xor(d2, m, 64);
            }
        }
        if (lane == 0) {
            sp[r][0] = d0; sp[r][1] = d1; sp[r][2] = d2;
            if (wp0 && t < len) p0[(size_t)b * TT + t] = d0;
        }
    };
    #pragma unroll 2
    for (int rr = 0; rr < 8; rr++) row_task(wv + rr * 8, true);   // 8 waves x 8 rows
    if (wv < 2) row_task(CH + wv, false);                          // 2 boundary rows
    __syncthreads();

    // --- windowed scores + chunk-local softmax: one wave per level -----------
    if (tid < 192) {
        const int i = wv;             // level 0..2
        const int r = lane;
        const int l = t0 + r;
        const bool valid = l < (len - i);              // window fully unmasked
        float s = sp[r][i];
        if (i > 0) s += sp[r + 1][i];
        if (i > 1) s += sp[r + 2][i];
        const float kin = (i == 0) ? 1.0f : ((i == 1) ? 0.5f : (1.0f / 3.0f));
        const float v = valid ? s * kin : NEG;
        float m = v;
        #pragma unroll
        for (int mm = 32; mm >= 1; mm >>= 1) m = fmaxf(m, __shfl_xor(m, mm, 64));
        const float u = valid ? __expf(v - m) : 0.f;
        su[i][r] = u;
        float ts = u;
        #pragma unroll
        for (int mm = 32; mm >= 1; mm >>= 1) ts += __shfl_xor(ts, mm, 64);
        if (r == 0) {
            mbuf[(size_t)(i * BB + b) * NY + y] = m;
            sbuf[(size_t)(i * BB + b) * NY + y] = ts;
        }
    }
    __syncthreads();

    // --- phase B: partial pooled = sum_l u_l * ngram_l (rolling 3-row window)
    // thread-per-column: 512 threads cover the full row, 64-deep pipelined loads
    const float* col = enc + (size_t)b * TT * DD + tid;
    float va = col[(size_t)t0 * DD];                   // t0 < len <= TT
    float vb2 = (t0 + 1 < TT) ? col[(size_t)(t0 + 1) * DD] : 0.f;
    float a0 = 0.f, a1 = 0.f, a2 = 0.f;
    #pragma unroll 16
    for (int rr = 0; rr < CH; rr++) {
        const int t = t0 + rr;
        const float vc = (t + 2 < TT) ? col[(size_t)(t + 2) * DD] : 0.f;
        const float u0 = su[0][rr], u1 = su[1][rr], u2 = su[2][rr];  // LDS broadcast
        const float w1 = va + vb2;
        const float w2 = w1 + vc;
        a0 += u0 * va;
        a1 += u1 * w1;
        a2 += u2 * w2;
        va = vb2; vb2 = vc;
    }
    a1 *= 0.5f; a2 *= (1.0f / 3.0f);
    float* pt = part + (size_t)y * BB * DD + (size_t)b * DD + tid;
    pt[0] = a0;
    pt[(size_t)NY * BB * DD] = a1;
    pt[(size_t)2 * NY * BB * DD] = a2;
}

// ------- K4: global softmax combine + pooled reduction (k_combine folded in) -
// 96 blocks: (i,b) x 2 d-halves. Wave 0 computes the 64 chunk scales in-LDS.
__global__ void __launch_bounds__(256) k_reduce(const float* __restrict__ part,
                                                const float* __restrict__ mbuf,
                                                const float* __restrict__ sbuf,
                                                float* __restrict__ pooled,
                                                float* __restrict__ mtot,
                                                float* __restrict__ tot) {
    __shared__ float ssc[NY];
    const int blk = blockIdx.x;
    const int ib = blk >> 1;                   // i*BB+b
    const int d = ((blk & 1) << 8) + threadIdx.x;
    const int i = ib / BB, b = ib % BB;
    if (threadIdx.x < 64) {
        const int lane = threadIdx.x;          // NY == 64: one chunk per lane
        const float ml = mbuf[(size_t)ib * NY + lane];
        const float sl = sbuf[(size_t)ib * NY + lane];
        float m = ml;
        #pragma unroll
        for (int s = 32; s >= 1; s >>= 1) m = fmaxf(m, __shfl_xor(m, s, 64));
        float t = sl * __expf(ml - m);
        #pragma unroll
        for (int s = 32; s >= 1; s >>= 1) t += __shfl_xor(t, s, 64);
        ssc[lane] = __expf(ml - m) / t;        // skipped chunks: exp(NEG-m)=0
        if (lane == 0 && (blk & 1) == 0) { mtot[ib] = m; tot[ib] = t; }
    }
    __syncthreads();
    const float* base = part + (size_t)i * NY * BB * DD + (size_t)b * DD + d;
    float s = 0.f;
    #pragma unroll 8
    for (int yy = 0; yy < NY; yy++) s += base[(size_t)yy * BB * DD] * ssc[yy];
    pooled[(size_t)ib * DD + d] = s;
}

// ------- K5: ctx (W-projection) + att (level-0 normalize), fused -------------
__global__ void __launch_bounds__(256) k_out(const float* __restrict__ pooled,
                                             const float* __restrict__ Ww,
                                             const float* __restrict__ Wb,
                                             const float* __restrict__ p0,
                                             const int* __restrict__ lengths,
                                             const float* __restrict__ mtot,
                                             const float* __restrict__ tot,
                                             float* __restrict__ ctx,
                                             float* __restrict__ att) {
    if (blockIdx.x < BB * DD / 4) {
        // ctx[b,e] = sum_i (pooled_i[b,:] . Ww[i,e,:]) + sum_i Wb[i,e]
        const int wid = blockIdx.x * 4 + (threadIdx.x >> 6);   // b*512 + e
        const int lane = threadIdx.x & 63;
        const int b = wid >> 9;
        const int e = wid & 511;
        float acc = 0.f;
        #pragma unroll
        for (int i = 0; i < 3; i++) {
            const float4* pr = (const float4*)(pooled + (size_t)(i * BB + b) * DD);
            const float4* wr = (const float4*)(Ww + ((size_t)i * DD + e) * DD);
            const float4 pA = pr[lane], pB = pr[64 + lane];
            const float4 wA = wr[lane], wB = wr[64 + lane];
            acc += pA.x * wA.x + pA.y * wA.y + pA.z * wA.z + pA.w * wA.w
                 + pB.x * wB.x + pB.y * wB.y + pB.z * wB.z + pB.w * wB.w;
        }
        #pragma unroll
        for (int m = 32; m >= 1; m >>= 1) acc += __shfl_xor(acc, m, 64);
        if (lane == 0)
            ctx[(size_t)b * DD + e] = acc + Wb[e] + Wb[DD + e] + Wb[2 * DD + e];
    } else {
        // att[b,t] = (t<len) ? exp(p0-m)/total : 0  (level 0)
        const int idx = (blockIdx.x - BB * DD / 4) * 256 + threadIdx.x;  // b*TT+t
        const int b = idx >> 12;
        const int t = idx & (TT - 1);
        att[idx] = (t < lengths[b]) ? __expf(p0[idx] - mtot[b]) * (1.0f / tot[b]) : 0.f;
    }
}

extern "C" void kernel_launch(void* const* d_in, const int* in_sizes, int n_in,
                              void* d_out, int out_size, void* d_ws, size_t ws_size,
                              hipStream_t stream) {
    const float* s_prev = (const float*)d_in[0];
    const float* enc    = (const float*)d_in[1];
    const void*  mask   = d_in[2];
    const float* Vw     = (const float*)d_in[3];
    // d_in[4] = Vb: dead — constant shift under softmax
    const float* Ww     = (const float*)d_in[5];
    const float* Wb     = (const float*)d_in[6];

    float* out = (float*)d_out;
    float* ctx = out;              // [B, D]
    float* att = out + BB * DD;    // [B, T]

    float* W       = (float*)d_ws;
    int*   lengths = (int*)d_ws;
    float* q       = W + OFF_Q;
    float* p0      = W + OFF_P0;
    float* mbuf    = W + OFF_M;
    float* sbuf    = W + OFF_S;
    float* mtot    = W + OFF_MT;
    float* tot     = W + OFF_TOT;
    float* part    = W + OFF_PART;
    float* pooled  = W + OFF_POOL;

    k_lengths<<<BB, 256, 0, stream>>>((const unsigned char*)mask, lengths);
    k_q<<<48, 1024, 0, stream>>>(s_prev, Vw, q);
    k_fused<<<dim3(BB, NY), 512, 0, stream>>>(enc, q, lengths, p0, mbuf, sbuf, part);
    k_reduce<<<96, 256, 0, stream>>>(part, mbuf, sbuf, pooled, mtot, tot);
    k_out<<<BB * DD / 4 + BB * TT / 256, 256, 0, stream>>>(pooled, Ww, Wb, p0, lengths,
                                                           mtot, tot, ctx, att);
}

// Round 3
// 251.337 us; speedup vs baseline: 1.0607x; 1.0181x over previous
//
#include <hip/hip_runtime.h>

#define BB 16
#define TT 4096
#define DD 512
#define CH 32               // rows per chunk in fused kernel (LDS-staged)
#define NY (TT/CH)          // 128 chunks per batch row
#define NEG (-1.0e30f)

// workspace float offsets
#define OFF_Q     64                         // 3*BB*DD
#define OFF_P0    (OFF_Q + 3*BB*DD)          // BB*TT      (level-0 dots for att)
#define OFF_M     (OFF_P0 + BB*TT)           // 3*BB*NY    (per-chunk local max)
#define OFF_S     (OFF_M + 3*BB*NY)          // 3*BB*NY    (per-chunk exp-sum)
#define OFF_MT    (OFF_S + 3*BB*NY)          // 64         (per-(i,b) global max)
#define OFF_TOT   (OFF_MT + 64)              // 64         (per-(i,b) total)
#define OFF_PART  (OFF_TOT + 64)             // 3*NY*BB*DD (pooled partials, 12.6MB)
#define OFF_POOL  (OFF_PART + 3*NY*BB*DD)    // 3*BB*DD

// ---------------- K1: mask layout detection + per-batch lengths --------------
__global__ void __launch_bounds__(256) k_lengths(const unsigned char* __restrict__ mask,
                                                 int* __restrict__ lengths) {
    __shared__ int sflag;
    __shared__ int wsum[4];
    const int tid = threadIdx.x;
    const int b = blockIdx.x;
    if (tid == 0) sflag = 0;
    __syncthreads();
    // layout probe: any nonzero byte at offset %4 != 0 => byte (bool) layout.
    const uint4* m4 = (const uint4*)mask;
    int f = 0;
    #pragma unroll 4
    for (int idx = tid; idx < BB * TT / 16; idx += 256) {
        const uint4 w = m4[idx];
        f |= (((w.x | w.y | w.z | w.w) & 0xFFFFFF00u) != 0u);
    }
    if (f) atomicOr(&sflag, 1);
    __syncthreads();
    const bool byte_layout = (sflag != 0);
    const int* m32 = (const int*)mask;
    int cnt = 0;
    if (byte_layout) {
        for (int t = tid; t < TT; t += 256) cnt += (mask[b * TT + t] != 0);
    } else {
        for (int t = tid; t < TT; t += 256) cnt += (m32[b * TT + t] != 0);
    }
    #pragma unroll
    for (int m = 32; m >= 1; m >>= 1) cnt += __shfl_xor(cnt, m, 64);
    if ((tid & 63) == 0) wsum[tid >> 6] = cnt;
    __syncthreads();
    if (tid == 0) lengths[b] = TT - (wsum[0] + wsum[1] + wsum[2] + wsum[3]);
}

// ------- K2: q[(i,b),d] = sum_e s_prev[b,e]*Vw[i,e,d]  (one block per (i,b)) -
__global__ void __launch_bounds__(1024) k_q(const float* __restrict__ s_prev,
                                            const float* __restrict__ Vw,
                                            float* __restrict__ q) {
    __shared__ float red[4][DD];
    const int ib = blockIdx.x;            // i*BB+b, 48 blocks
    const int b = ib % BB;
    const int i = ib / BB;
    const int ec = threadIdx.x >> 8;      // e-quarter, wave-uniform
    const int d0 = threadIdx.x & 255;
    const float* sp = s_prev + b * DD + ec * 128;
    const float* W = Vw + (size_t)i * DD * DD + (size_t)(ec * 128) * DD;
    float a0 = 0.f, a1 = 0.f;
    #pragma unroll 4
    for (int e = 0; e < 128; e++) {
        const float se = sp[e];           // wave-uniform -> scalar load
        a0 += se * W[e * DD + d0];
        a1 += se * W[e * DD + d0 + 256];
    }
    red[ec][d0] = a0;
    red[ec][d0 + 256] = a1;
    __syncthreads();
    if (threadIdx.x < DD)
        q[(size_t)ib * DD + threadIdx.x] = red[0][threadIdx.x] + red[1][threadIdx.x]
                                         + red[2][threadIdx.x] + red[3][threadIdx.x];
}

// ---- K3 fused: dots + LDS-staged rows + windowed softmax + pooling ----------
// Block = (b, chunk y): rows [t0, t0+CH) plus 2 boundary rows. 512 threads.
// enc is read from global exactly ONCE (phase A); phase B consumes the LDS copy.
__global__ void __launch_bounds__(512, 4) k_fused(const float* __restrict__ enc,
                                                  const float* __restrict__ q,
                                                  const int* __restrict__ lengths,
                                                  float* __restrict__ p0,
                                                  float* __restrict__ mbuf,
                                                  float* __restrict__ sbuf,
                                                  float* __restrict__ part) {
    __shared__ float se[CH + 2][DD];  // 68 KB: staged enc rows (zero-filled past TT)
    __shared__ float sp[CH + 2][3];   // per-row dots, 3 levels
    __shared__ float su[3][CH];       // raw exp weights
    const int b = blockIdx.x;
    const int y = blockIdx.y;
    const int t0 = y * CH;
    const int len = lengths[b];
    const int tid = threadIdx.x;
    if (t0 >= len) {                  // fully masked chunk (block-uniform)
        if (tid < 3) {
            mbuf[(size_t)(tid * BB + b) * NY + y] = NEG;
            sbuf[(size_t)(tid * BB + b) * NY + y] = 0.f;
        }
        return;
    }
    const int wv = tid >> 6, lane = tid & 63;

    // --- phase A: dots p_i[t] = enc[t].q_i[b], rows staged to LDS ------------
    const float4* q40 = (const float4*)(q + (size_t)(0 * BB + b) * DD);
    const float4* q41 = (const float4*)(q + (size_t)(1 * BB + b) * DD);
    const float4* q42 = (const float4*)(q + (size_t)(2 * BB + b) * DD);
    const float4 qa0 = q40[lane], qb0 = q40[64 + lane];
    const float4 qa1 = q41[lane], qb1 = q41[64 + lane];
    const float4 qa2 = q42[lane], qb2 = q42[64 + lane];

    auto row_task = [&](const int r, const bool wp0) {
        const int t = t0 + r;
        float4 x0 = make_float4(0.f, 0.f, 0.f, 0.f), x1 = x0;
        if (t < TT) {                                   // wave-uniform
            const float4* e4 = (const float4*)(enc + ((size_t)b * TT + t) * DD);
            x0 = e4[lane]; x1 = e4[64 + lane];
        }
        ((float4*)se[r])[lane] = x0;                    // stage row in LDS
        ((float4*)se[r])[64 + lane] = x1;
        float d0 = x0.x*qa0.x + x0.y*qa0.y + x0.z*qa0.z + x0.w*qa0.w
                 + x1.x*qb0.x + x1.y*qb0.y + x1.z*qb0.z + x1.w*qb0.w;
        float d1 = x0.x*qa1.x + x0.y*qa1.y + x0.z*qa1.z + x0.w*qa1.w
                 + x1.x*qb1.x + x1.y*qb1.y + x1.z*qb1.z + x1.w*qb1.w;
        float d2 = x0.x*qa2.x + x0.y*qa2.y + x0.z*qa2.z + x0.w*qa2.w
                 + x1.x*qb2.x + x1.y*qb2.y + x1.z*qb2.z + x1.w*qb2.w;
        #pragma unroll
        for (int m = 32; m >= 1; m >>= 1) {
            d0 += __shfl_xor(d0, m, 64);
            d1 += __shfl_xor(d1, m, 64);
            d2 += __shfl_xor(d2, m, 64);
        }
        if (lane == 0) {
            sp[r][0] = d0; sp[r][1] = d1; sp[r][2] = d2;
            if (wp0 && t < TT) p0[(size_t)b * TT + t] = d0;  // t>=len masked later
        }
    };
    #pragma unroll
    for (int rr = 0; rr < 4; rr++) row_task(wv + rr * 8, true);   // 8 waves x 4 rows
    if (wv < 2) row_task(CH + wv, false);                          // 2 boundary rows
    __syncthreads();

    // --- windowed scores + chunk-local softmax: one wave per level -----------
    if (tid < 192) {
        const int i = wv;             // level 0..2
        const bool act = lane < CH;
        const int r = lane & (CH - 1);
        const int l = t0 + r;
        const bool valid = act && (l < (len - i));     // window fully unmasked
        float v = NEG;
        if (act) {
            float s = sp[r][i];
            if (i > 0) s += sp[r + 1][i];
            if (i > 1) s += sp[r + 2][i];
            const float kin = (i == 0) ? 1.0f : ((i == 1) ? 0.5f : (1.0f / 3.0f));
            v = valid ? s * kin : NEG;
        }
        float m = v;
        #pragma unroll
        for (int mm = 32; mm >= 1; mm >>= 1) m = fmaxf(m, __shfl_xor(m, mm, 64));
        const float u = valid ? __expf(v - m) : 0.f;
        if (act) su[i][r] = u;
        float ts = u;
        #pragma unroll
        for (int mm = 32; mm >= 1; mm >>= 1) ts += __shfl_xor(ts, mm, 64);
        if (lane == 0) {
            mbuf[(size_t)(i * BB + b) * NY + y] = m;
            sbuf[(size_t)(i * BB + b) * NY + y] = ts;
        }
    }
    __syncthreads();

    // --- phase B: partial pooled = sum_l u_l * ngram_l, all from LDS ---------
    // thread-per-column; rolling 3-row window; weights read as float4 broadcast
    float va = se[0][tid], vb2 = se[1][tid];
    float a0 = 0.f, a1 = 0.f, a2 = 0.f;
    #pragma unroll
    for (int g = 0; g < CH / 4; g++) {
        const float4 U0 = *(const float4*)&su[0][g * 4];
        const float4 U1 = *(const float4*)&su[1][g * 4];
        const float4 U2 = *(const float4*)&su[2][g * 4];
        const float u0a[4] = {U0.x, U0.y, U0.z, U0.w};
        const float u1a[4] = {U1.x, U1.y, U1.z, U1.w};
        const float u2a[4] = {U2.x, U2.y, U2.z, U2.w};
        #pragma unroll
        for (int j = 0; j < 4; j++) {
            const float vc = se[g * 4 + j + 2][tid];
            const float w1 = va + vb2;
            const float w2 = w1 + vc;
            a0 += u0a[j] * va;
            a1 += u1a[j] * w1;
            a2 += u2a[j] * w2;
            va = vb2; vb2 = vc;
        }
    }
    a1 *= 0.5f; a2 *= (1.0f / 3.0f);
    float* pt = part + (size_t)y * BB * DD + (size_t)b * DD + tid;
    pt[0] = a0;
    pt[(size_t)NY * BB * DD] = a1;
    pt[(size_t)2 * NY * BB * DD] = a2;
}

// ------- K4: global softmax combine + pooled reduction -----------------------
// 96 blocks: (i,b) x 2 d-halves. Wave 0 computes the 128 chunk scales in-LDS.
__global__ void __launch_bounds__(256) k_reduce(const float* __restrict__ part,
                                                const float* __restrict__ mbuf,
                                                const float* __restrict__ sbuf,
                                                float* __restrict__ pooled,
                                                float* __restrict__ mtot,
                                                float* __restrict__ tot) {
    __shared__ float ssc[NY];
    const int blk = blockIdx.x;
    const int ib = blk >> 1;                   // i*BB+b
    const int d = ((blk & 1) << 8) + threadIdx.x;
    const int i = ib / BB, b = ib % BB;
    if (threadIdx.x < 64) {
        const int lane = threadIdx.x;          // NY == 128: two chunks per lane
        float ml[2], sl[2];
        float m = NEG;
        #pragma unroll
        for (int j = 0; j < 2; j++) {
            ml[j] = mbuf[(size_t)ib * NY + lane * 2 + j];
            sl[j] = sbuf[(size_t)ib * NY + lane * 2 + j];
            m = fmaxf(m, ml[j]);
        }
        #pragma unroll
        for (int s = 32; s >= 1; s >>= 1) m = fmaxf(m, __shfl_xor(m, s, 64));
        float t = 0.f;
        #pragma unroll
        for (int j = 0; j < 2; j++) t += sl[j] * __expf(ml[j] - m);
        #pragma unroll
        for (int s = 32; s >= 1; s >>= 1) t += __shfl_xor(t, s, 64);
        const float inv = 1.0f / t;
        #pragma unroll
        for (int j = 0; j < 2; j++)
            ssc[lane * 2 + j] = __expf(ml[j] - m) * inv;  // skipped chunks -> 0
        if (lane == 0 && (blk & 1) == 0) { mtot[ib] = m; tot[ib] = t; }
    }
    __syncthreads();
    const float* base = part + (size_t)i * NY * BB * DD + (size_t)b * DD + d;
    float s = 0.f;
    #pragma unroll 8
    for (int yy = 0; yy < NY; yy++) s += base[(size_t)yy * BB * DD] * ssc[yy];
    pooled[(size_t)ib * DD + d] = s;
}

// ------- K5: ctx (W-projection) + att (level-0 normalize), fused -------------
__global__ void __launch_bounds__(256) k_out(const float* __restrict__ pooled,
                                             const float* __restrict__ Ww,
                                             const float* __restrict__ Wb,
                                             const float* __restrict__ p0,
                                             const int* __restrict__ lengths,
                                             const float* __restrict__ mtot,
                                             const float* __restrict__ tot,
                                             float* __restrict__ ctx,
                                             float* __restrict__ att) {
    if (blockIdx.x < BB * DD / 4) {
        // ctx[b,e] = sum_i (pooled_i[b,:] . Ww[i,e,:]) + sum_i Wb[i,e]
        const int wid = blockIdx.x * 4 + (threadIdx.x >> 6);   // b*512 + e
        const int lane = threadIdx.x & 63;
        const int b = wid >> 9;
        const int e = wid & 511;
        float acc = 0.f;
        #pragma unroll
        for (int i = 0; i < 3; i++) {
            const float4* pr = (const float4*)(pooled + (size_t)(i * BB + b) * DD);
            const float4* wr = (const float4*)(Ww + ((size_t)i * DD + e) * DD);
            const float4 pA = pr[lane], pB = pr[64 + lane];
            const float4 wA = wr[lane], wB = wr[64 + lane];
            acc += pA.x * wA.x + pA.y * wA.y + pA.z * wA.z + pA.w * wA.w
                 + pB.x * wB.x + pB.y * wB.y + pB.z * wB.z + pB.w * wB.w;
        }
        #pragma unroll
        for (int m = 32; m >= 1; m >>= 1) acc += __shfl_xor(acc, m, 64);
        if (lane == 0)
            ctx[(size_t)b * DD + e] = acc + Wb[e] + Wb[DD + e] + Wb[2 * DD + e];
    } else {
        // att[b,t] = (t<len) ? exp(p0-m)/total : 0  (level 0)
        const int idx = (blockIdx.x - BB * DD / 4) * 256 + threadIdx.x;  // b*TT+t
        const int b = idx >> 12;
        const int t = idx & (TT - 1);
        att[idx] = (t < lengths[b]) ? __expf(p0[idx] - mtot[b]) * (1.0f / tot[b]) : 0.f;
    }
}

extern "C" void kernel_launch(void* const* d_in, const int* in_sizes, int n_in,
                              void* d_out, int out_size, void* d_ws, size_t ws_size,
                              hipStream_t stream) {
    const float* s_prev = (const float*)d_in[0];
    const float* enc    = (const float*)d_in[1];
    const void*  mask   = d_in[2];
    const float* Vw     = (const float*)d_in[3];
    // d_in[4] = Vb: dead — constant shift under softmax
    const float* Ww     = (const float*)d_in[5];
    const float* Wb     = (const float*)d_in[6];

    float* out = (float*)d_out;
    float* ctx = out;              // [B, D]
    float* att = out + BB * DD;    // [B, T]

    float* W       = (float*)d_ws;
    int*   lengths = (int*)d_ws;
    float* q       = W + OFF_Q;
    float* p0      = W + OFF_P0;
    float* mbuf    = W + OFF_M;
    float* sbuf    = W + OFF_S;
    float* mtot    = W + OFF_MT;
    float* tot     = W + OFF_TOT;
    float* part    = W + OFF_PART;
    float* pooled  = W + OFF_POOL;

    k_lengths<<<BB, 256, 0, stream>>>((const unsigned char*)mask, lengths);
    k_q<<<48, 1024, 0, stream>>>(s_prev, Vw, q);
    k_fused<<<dim3(BB, NY), 512, 0, stream>>>(enc, q, lengths, p0, mbuf, sbuf, part);
    k_reduce<<<96, 256, 0, stream>>>(part, mbuf, sbuf, pooled, mtot, tot);
    k_out<<<BB * DD / 4 + BB * TT / 256, 256, 0, stream>>>(pooled, Ww, Wb, p0, lengths,
                                                           mtot, tot, ctx, att);
}

// Round 4
// 227.744 us; speedup vs baseline: 1.1706x; 1.1036x over previous
//
#include <hip/hip_runtime.h>

#define BB 16
#define TT 4096
#define DD 512
#define CH 32               // rows per sub-chunk (LDS-staged)
#define GR 4                // sub-chunks per block (online-softmax combined)
#define NG (TT/(CH*GR))     // 32 groups per batch row
#define NEG (-1.0e30f)

// workspace float offsets
#define OFF_Q     64                         // 3*BB*DD
#define OFF_QP    (OFF_Q + 3*BB*DD)          // 8*3*BB*DD  (e-split q partials)
#define OFF_P0    (OFF_QP + 8*3*BB*DD)       // BB*TT      (level-0 dots for att)
#define OFF_M     (OFF_P0 + BB*TT)           // 3*BB*NG    (per-group local max)
#define OFF_S     (OFF_M + 3*BB*NG)          // 3*BB*NG    (per-group exp-sum)
#define OFF_MT    (OFF_S + 3*BB*NG)          // 64         (per-(i,b) global max)
#define OFF_TOT   (OFF_MT + 64)              // 64         (per-(i,b) total)
#define OFF_PART  (OFF_TOT + 64)             // 3*NG*BB*DD (pooled partials, 3.1MB)
#define OFF_POOL  (OFF_PART + 3*NG*BB*DD)    // 3*BB*DD

// ------- K1 fused pre-pass: lengths (blocks 0..15) + q e-split partials ------
// q role: block = (ib, ec) with 8 e-splits of 64; 256 threads, float4 Vw loads.
__global__ void __launch_bounds__(256) k_pre(const unsigned char* __restrict__ mask,
                                             const float* __restrict__ s_prev,
                                             const float* __restrict__ Vw,
                                             int* __restrict__ lengths,
                                             float* __restrict__ qpart) {
    const int tid = threadIdx.x;
    if (blockIdx.x < BB) {
        // ---- lengths role: mask layout detection + count ----
        __shared__ int sflag;
        __shared__ int wsum[4];
        const int b = blockIdx.x;
        if (tid == 0) sflag = 0;
        __syncthreads();
        // probe: any nonzero byte at offset %4 != 0 => byte (bool) layout
        const uint4* m4 = (const uint4*)mask;
        int f = 0;
        #pragma unroll 4
        for (int idx = tid; idx < BB * TT / 16; idx += 256) {
            const uint4 w = m4[idx];
            f |= (((w.x | w.y | w.z | w.w) & 0xFFFFFF00u) != 0u);
        }
        if (f) atomicOr(&sflag, 1);
        __syncthreads();
        const bool byte_layout = (sflag != 0);
        const int* m32 = (const int*)mask;
        int cnt = 0;
        if (byte_layout) {
            for (int t = tid; t < TT; t += 256) cnt += (mask[b * TT + t] != 0);
        } else {
            for (int t = tid; t < TT; t += 256) cnt += (m32[b * TT + t] != 0);
        }
        #pragma unroll
        for (int m = 32; m >= 1; m >>= 1) cnt += __shfl_xor(cnt, m, 64);
        if ((tid & 63) == 0) wsum[tid >> 6] = cnt;
        __syncthreads();
        if (tid == 0) lengths[b] = TT - (wsum[0] + wsum[1] + wsum[2] + wsum[3]);
    } else {
        // ---- q-partial role: qpart[(ib,ec),d] = sum_{e in 64-range} s_prev*Vw ----
        __shared__ float4 red[2][128];
        const int idx = blockIdx.x - BB;      // ib*8 + ec, 384 blocks
        const int ib = idx >> 3;
        const int ec = idx & 7;
        const int b = ib % BB;
        const int i = ib / BB;
        const int es = tid >> 7;              // 2-way e-split (wave-uniform)
        const int dq = tid & 127;             // d-quad
        const int e0 = ec * 64 + es * 32;
        const float* sp = s_prev + b * DD + e0;
        const float4* W = (const float4*)(Vw + (size_t)i * DD * DD + (size_t)e0 * DD) + dq;
        float4 acc = make_float4(0.f, 0.f, 0.f, 0.f);
        #pragma unroll 8
        for (int e = 0; e < 32; e++) {
            const float sev = sp[e];          // wave-uniform -> scalar load
            const float4 w = W[e * 128];
            acc.x += sev * w.x; acc.y += sev * w.y;
            acc.z += sev * w.z; acc.w += sev * w.w;
        }
        red[es][dq] = acc;
        __syncthreads();
        if (tid < 128) {
            const float4 r0 = red[0][tid], r1 = red[1][tid];
            const float4 o = make_float4(r0.x + r1.x, r0.y + r1.y,
                                         r0.z + r1.z, r0.w + r1.w);
            ((float4*)(qpart + (size_t)idx * DD))[tid] = o;
        }
    }
}

// ------- K2: q[(i,b),d] = sum_ec qpart[(ib,ec),d] ----------------------------
__global__ void __launch_bounds__(256) k_q2(const float* __restrict__ qpart,
                                            float* __restrict__ q) {
    const int idx = blockIdx.x * 256 + threadIdx.x;  // ib*DD + d, 24576
    const int ib = idx / DD;
    const int d = idx % DD;
    float s = 0.f;
    #pragma unroll
    for (int ec = 0; ec < 8; ec++) s += qpart[(size_t)(ib * 8 + ec) * DD + d];
    q[idx] = s;
}

// ---- K3 fused: 4 sub-chunks per block, online-softmax (flash) combine -------
// Block = (b, group g): rows [t0g, t0g+128) in 4 LDS-staged sub-chunks of 32.
// enc read from global exactly once; per-level running (M,S,A) in registers.
__global__ void __launch_bounds__(512, 4) k_fused(const float* __restrict__ enc,
                                                  const float* __restrict__ q,
                                                  const int* __restrict__ lengths,
                                                  float* __restrict__ p0,
                                                  float* __restrict__ mbuf,
                                                  float* __restrict__ sbuf,
                                                  float* __restrict__ part) {
    __shared__ float se[CH + 2][DD];  // 68 KB: staged enc rows (zero past TT)
    __shared__ float sp[CH + 2][3];   // per-row dots, 3 levels
    __shared__ float su[3][CH];       // raw exp weights (this sub-chunk)
    __shared__ float sms[3], sss[3];  // sub-chunk local max / exp-sum
    const int b = blockIdx.x;
    const int g = blockIdx.y;
    const int t0g = g * (CH * GR);
    const int len = lengths[b];
    const int tid = threadIdx.x;
    if (t0g >= len) {                 // fully masked group (block-uniform)
        if (tid < 3) {
            mbuf[(size_t)(tid * BB + b) * NG + g] = NEG;
            sbuf[(size_t)(tid * BB + b) * NG + g] = 0.f;
        }
        return;
    }
    const int wv = tid >> 6, lane = tid & 63;

    const float4* q40 = (const float4*)(q + (size_t)(0 * BB + b) * DD);
    const float4* q41 = (const float4*)(q + (size_t)(1 * BB + b) * DD);
    const float4* q42 = (const float4*)(q + (size_t)(2 * BB + b) * DD);
    const float4 qa0 = q40[lane], qb0 = q40[64 + lane];
    const float4 qa1 = q41[lane], qb1 = q41[64 + lane];
    const float4 qa2 = q42[lane], qb2 = q42[64 + lane];

    float M0 = NEG, M1 = NEG, M2 = NEG;       // running max per level
    float S0 = 0.f, S1 = 0.f, S2 = 0.f;       // running exp-sum per level
    float A0 = 0.f, A1 = 0.f, A2 = 0.f;       // running weighted col-sum

    for (int sub = 0; sub < GR; sub++) {
        const int t0 = t0g + sub * CH;
        if (t0 >= len) break;                 // block-uniform
        if (sub) __syncthreads();             // protect se/su reuse

        // --- phase A: dots + stage rows t0..t0+33 into LDS -------------------
        auto row_task = [&](const int r, const bool wp0) {
            const int t = t0 + r;
            float4 x0 = make_float4(0.f, 0.f, 0.f, 0.f), x1 = x0;
            if (t < TT) {                                   // wave-uniform
                const float4* e4 = (const float4*)(enc + ((size_t)b * TT + t) * DD);
                x0 = e4[lane]; x1 = e4[64 + lane];
            }
            ((float4*)se[r])[lane] = x0;
            ((float4*)se[r])[64 + lane] = x1;
            float d0 = x0.x*qa0.x + x0.y*qa0.y + x0.z*qa0.z + x0.w*qa0.w
                     + x1.x*qb0.x + x1.y*qb0.y + x1.z*qb0.z + x1.w*qb0.w;
            float d1 = x0.x*qa1.x + x0.y*qa1.y + x0.z*qa1.z + x0.w*qa1.w
                     + x1.x*qb1.x + x1.y*qb1.y + x1.z*qb1.z + x1.w*qb1.w;
            float d2 = x0.x*qa2.x + x0.y*qa2.y + x0.z*qa2.z + x0.w*qa2.w
                     + x1.x*qb2.x + x1.y*qb2.y + x1.z*qb2.z + x1.w*qb2.w;
            #pragma unroll
            for (int m = 32; m >= 1; m >>= 1) {
                d0 += __shfl_xor(d0, m, 64);
                d1 += __shfl_xor(d1, m, 64);
                d2 += __shfl_xor(d2, m, 64);
            }
            if (lane == 0) {
                sp[r][0] = d0; sp[r][1] = d1; sp[r][2] = d2;
                if (wp0 && t < TT) p0[(size_t)b * TT + t] = d0;  // masked in k_out
            }
        };
        #pragma unroll
        for (int rr = 0; rr < 4; rr++) row_task(wv + rr * 8, true);  // 8 waves x 4
        if (wv < 2) row_task(CH + wv, false);                         // 2 boundary
        __syncthreads();

        // --- windowed scores + sub-chunk softmax: one wave per level ---------
        if (tid < 192) {
            const int i = wv;
            const bool act = lane < CH;
            const int r = lane & (CH - 1);
            const int l = t0 + r;
            const bool valid = act && (l < (len - i));
            float v = NEG;
            if (act) {
                float s = sp[r][i];
                if (i > 0) s += sp[r + 1][i];
                if (i > 1) s += sp[r + 2][i];
                const float kin = (i == 0) ? 1.0f : ((i == 1) ? 0.5f : (1.0f / 3.0f));
                v = valid ? s * kin : NEG;
            }
            float m = v;
            #pragma unroll
            for (int mm = 32; mm >= 1; mm >>= 1) m = fmaxf(m, __shfl_xor(m, mm, 64));
            const float u = valid ? __expf(v - m) : 0.f;
            if (act) su[i][r] = u;
            float ts = u;
            #pragma unroll
            for (int mm = 32; mm >= 1; mm >>= 1) ts += __shfl_xor(ts, mm, 64);
            if (lane == 0) { sms[i] = m; sss[i] = ts; }
        }
        __syncthreads();

        // --- phase B: this sub-chunk's weighted col-sums from LDS ------------
        float va = se[0][tid], vb2 = se[1][tid];
        float a0 = 0.f, a1 = 0.f, a2 = 0.f;
        #pragma unroll
        for (int gg = 0; gg < CH / 4; gg++) {
            const float4 U0 = *(const float4*)&su[0][gg * 4];
            const float4 U1 = *(const float4*)&su[1][gg * 4];
            const float4 U2 = *(const float4*)&su[2][gg * 4];
            const float u0a[4] = {U0.x, U0.y, U0.z, U0.w};
            const float u1a[4] = {U1.x, U1.y, U1.z, U1.w};
            const float u2a[4] = {U2.x, U2.y, U2.z, U2.w};
            #pragma unroll
            for (int j = 0; j < 4; j++) {
                const float vc = se[gg * 4 + j + 2][tid];
                const float w1 = va + vb2;
                const float w2 = w1 + vc;
                a0 += u0a[j] * va;
                a1 += u1a[j] * w1;
                a2 += u2a[j] * w2;
                va = vb2; vb2 = vc;
            }
        }
        // --- flash combine (block-uniform m_j/s_j from LDS, all threads) -----
        const float m0j = sms[0], m1j = sms[1], m2j = sms[2];
        const float s0j = sss[0], s1j = sss[1], s2j = sss[2];
        {
            const float nM = fmaxf(M0, m0j);
            const float so = __expf(M0 - nM), sn = __expf(m0j - nM);
            A0 = A0 * so + a0 * sn;  S0 = S0 * so + s0j * sn;  M0 = nM;
        }
        {
            const float nM = fmaxf(M1, m1j);
            const float so = __expf(M1 - nM), sn = __expf(m1j - nM);
            A1 = A1 * so + a1 * sn;  S1 = S1 * so + s1j * sn;  M1 = nM;
        }
        {
            const float nM = fmaxf(M2, m2j);
            const float so = __expf(M2 - nM), sn = __expf(m2j - nM);
            A2 = A2 * so + a2 * sn;  S2 = S2 * so + s2j * sn;  M2 = nM;
        }
    }
    A1 *= 0.5f; A2 *= (1.0f / 3.0f);
    float* pt = part + (size_t)g * BB * DD + (size_t)b * DD + tid;
    pt[0] = A0;
    pt[(size_t)NG * BB * DD] = A1;
    pt[(size_t)2 * NG * BB * DD] = A2;
    if (tid < 3) {
        const float Mv = (tid == 0) ? M0 : ((tid == 1) ? M1 : M2);
        const float Sv = (tid == 0) ? S0 : ((tid == 1) ? S1 : S2);
        mbuf[(size_t)(tid * BB + b) * NG + g] = Mv;
        sbuf[(size_t)(tid * BB + b) * NG + g] = Sv;
    }
}

// ------- K4: global softmax combine + pooled reduction -----------------------
// 96 blocks: (i,b) x 2 d-halves. Wave 0 computes the 32 group scales in-LDS.
__global__ void __launch_bounds__(256) k_reduce(const float* __restrict__ part,
                                                const float* __restrict__ mbuf,
                                                const float* __restrict__ sbuf,
                                                float* __restrict__ pooled,
                                                float* __restrict__ mtot,
                                                float* __restrict__ tot) {
    __shared__ float ssc[NG];
    const int blk = blockIdx.x;
    const int ib = blk >> 1;                   // i*BB+b
    const int d = ((blk & 1) << 8) + threadIdx.x;
    const int i = ib / BB, b = ib % BB;
    if (threadIdx.x < 64) {
        const int lane = threadIdx.x;
        const bool a = lane < NG;              // NG == 32: one group per lane
        const float ml = a ? mbuf[(size_t)ib * NG + lane] : NEG;
        const float sl = a ? sbuf[(size_t)ib * NG + lane] : 0.f;
        float m = ml;
        #pragma unroll
        for (int s = 32; s >= 1; s >>= 1) m = fmaxf(m, __shfl_xor(m, s, 64));
        float t = sl * __expf(ml - m);
        #pragma unroll
        for (int s = 32; s >= 1; s >>= 1) t += __shfl_xor(t, s, 64);
        const float inv = 1.0f / t;
        if (a) ssc[lane] = __expf(ml - m) * inv;    // skipped groups -> 0
        if (lane == 0 && (blk & 1) == 0) { mtot[ib] = m; tot[ib] = t; }
    }
    __syncthreads();
    const float* base = part + (size_t)i * NG * BB * DD + (size_t)b * DD + d;
    float s = 0.f;
    #pragma unroll
    for (int yy = 0; yy < NG; yy++) {
        const float sc = ssc[yy];
        const float v = (sc != 0.f) ? base[(size_t)yy * BB * DD] : 0.f;  // poison-safe
        s += v * sc;
    }
    pooled[(size_t)ib * DD + d] = s;
}

// ------- K5: ctx (W-projection) + att (level-0 normalize), fused -------------
__global__ void __launch_bounds__(256) k_out(const float* __restrict__ pooled,
                                             const float* __restrict__ Ww,
                                             const float* __restrict__ Wb,
                                             const float* __restrict__ p0,
                                             const int* __restrict__ lengths,
                                             const float* __restrict__ mtot,
                                             const float* __restrict__ tot,
                                             float* __restrict__ ctx,
                                             float* __restrict__ att) {
    if (blockIdx.x < BB * DD / 4) {
        // ctx[b,e] = sum_i (pooled_i[b,:] . Ww[i,e,:]) + sum_i Wb[i,e]
        const int wid = blockIdx.x * 4 + (threadIdx.x >> 6);   // b*512 + e
        const int lane = threadIdx.x & 63;
        const int b = wid >> 9;
        const int e = wid & 511;
        float acc = 0.f;
        #pragma unroll
        for (int i = 0; i < 3; i++) {
            const float4* pr = (const float4*)(pooled + (size_t)(i * BB + b) * DD);
            const float4* wr = (const float4*)(Ww + ((size_t)i * DD + e) * DD);
            const float4 pA = pr[lane], pB = pr[64 + lane];
            const float4 wA = wr[lane], wB = wr[64 + lane];
            acc += pA.x * wA.x + pA.y * wA.y + pA.z * wA.z + pA.w * wA.w
                 + pB.x * wB.x + pB.y * wB.y + pB.z * wB.z + pB.w * wB.w;
        }
        #pragma unroll
        for (int m = 32; m >= 1; m >>= 1) acc += __shfl_xor(acc, m, 64);
        if (lane == 0)
            ctx[(size_t)b * DD + e] = acc + Wb[e] + Wb[DD + e] + Wb[2 * DD + e];
    } else {
        // att[b,t] = (t<len) ? exp(p0-m)/total : 0  (level 0)
        const int idx = (blockIdx.x - BB * DD / 4) * 256 + threadIdx.x;  // b*TT+t
        const int b = idx >> 12;
        const int t = idx & (TT - 1);
        att[idx] = (t < lengths[b]) ? __expf(p0[idx] - mtot[b]) * (1.0f / tot[b]) : 0.f;
    }
}

extern "C" void kernel_launch(void* const* d_in, const int* in_sizes, int n_in,
                              void* d_out, int out_size, void* d_ws, size_t ws_size,
                              hipStream_t stream) {
    const float* s_prev = (const float*)d_in[0];
    const float* enc    = (const float*)d_in[1];
    const void*  mask   = d_in[2];
    const float* Vw     = (const float*)d_in[3];
    // d_in[4] = Vb: dead — constant shift under softmax
    const float* Ww     = (const float*)d_in[5];
    const float* Wb     = (const float*)d_in[6];

    float* out = (float*)d_out;
    float* ctx = out;              // [B, D]
    float* att = out + BB * DD;    // [B, T]

    float* W       = (float*)d_ws;
    int*   lengths = (int*)d_ws;
    float* q       = W + OFF_Q;
    float* qpart   = W + OFF_QP;
    float* p0      = W + OFF_P0;
    float* mbuf    = W + OFF_M;
    float* sbuf    = W + OFF_S;
    float* mtot    = W + OFF_MT;
    float* tot     = W + OFF_TOT;
    float* part    = W + OFF_PART;
    float* pooled  = W + OFF_POOL;

    k_pre<<<BB + 48 * 8, 256, 0, stream>>>((const unsigned char*)mask, s_prev, Vw,
                                           lengths, qpart);
    k_q2<<<3 * BB * DD / 256, 256, 0, stream>>>(qpart, q);
    k_fused<<<dim3(BB, NG), 512, 0, stream>>>(enc, q, lengths, p0, mbuf, sbuf, part);
    k_reduce<<<96, 256, 0, stream>>>(part, mbuf, sbuf, pooled, mtot, tot);
    k_out<<<BB * DD / 4 + BB * TT / 256, 256, 0, stream>>>(pooled, Ww, Wb, p0, lengths,
                                                           mtot, tot, ctx, att);
}